// Round 2
// baseline (681.792 us; speedup 1.0000x reference)
//
#include <hip/hip_runtime.h>

// TestEBCModel: jagged embedding gather + SUM pool (T=4,B=8192,L=50,VOCAB=100000,D=128)
// followed by 3 stacked Linear(D,D) with no activation.
// Affine fold: M = W1^T W2^T W3^T, c = (b1 W2^T + b2) W3^T + b3.
// R5: barrier-free work-stealing. One global bag counter (zeroed by combine); each
// wave steals one bag at a time -> perfect chip-wide balance. Per-wave LDS slots
// (offsets + 4 pooled rows), wave-local s_waitcnt lgkmcnt(0) instead of any
// __syncthreads. Gather: float4 half-split (lanes 0-31 even positions, 32-63 odd),
// unroll 16 -> 8x1KB loads in flight per wave. Every 4 pooled bags: inline 4-row
// matvec (out = p @ M + c) sharing M float2 loads across the 4 rows (M L2 traffic
// same as old phase-2). Decisive test: concurrency/balance vs random-gather
// memory-system cap.

#define T_ 4
#define B_ 8192
#define L_ 50
#define VOCAB_ 100000
#define D_ 128
#define NBAGS (T_ * B_)

// ws layout (floats): M[16384] | c[128] | bag counter (1 int)
#define WS_M   0
#define WS_C   16384
#define WS_CTR 16512

// ---- merged combine: M = (W1^T W2^T) W3^T ; c = ((b1 W2^T + b2)) W3^T + b3 ----
// blocks 0..127 compute M row i; block 128 computes c and zeroes the bag counter.
__global__ __launch_bounds__(128) void combine(const float* __restrict__ W1,
                                               const float* __restrict__ W2,
                                               const float* __restrict__ W3,
                                               const float* __restrict__ b1,
                                               const float* __restrict__ b2,
                                               const float* __restrict__ b3,
                                               float* __restrict__ ws) {
  __shared__ float a1[D_];
  const int j = threadIdx.x;
  const int i = blockIdx.x;
  if (i < D_) {
    float acc = 0.f;
    for (int k = 0; k < D_; ++k)
      acc += W1[k * D_ + i] * W2[j * D_ + k];
    a1[j] = acc;
    __syncthreads();
    float m = 0.f;
    for (int k = 0; k < D_; ++k)
      m += a1[k] * W3[j * D_ + k];
    ws[WS_M + i * D_ + j] = m;
  } else {
    if (j == 0) ((int*)ws)[WS_CTR] = 0;   // reset steal counter every iteration
    float c1 = b2[j];
    for (int k = 0; k < D_; ++k)
      c1 += b1[k] * W2[j * D_ + k];
    a1[j] = c1;
    __syncthreads();
    float c = b3[j];
    for (int k = 0; k < D_; ++k)
      c += a1[k] * W3[j * D_ + k];
    ws[WS_C + j] = c;
  }
}

// ---- fused: barrier-free work-stealing pool + inline 4-row matvec ----
__global__ __launch_bounds__(256, 4) void fused(const int* __restrict__ indices,
                                                const int* __restrict__ lengths,
                                                const float* __restrict__ tables,
                                                float* __restrict__ ws,
                                                float* __restrict__ out) {
  __shared__ __align__(16) float p_sh[4][4][D_];  // [wave][slot][128]
  __shared__ int off_sh[4][64];                   // [wave][pos] row byte offsets

  const int wid  = threadIdx.x >> 6;
  const int lane = threadIdx.x & 63;
  const int half = lane >> 5;           // 0: even positions, 1: odd positions
  const int d0   = (lane & 31) * 4;     // gather: 4 floats/lane, 32 lanes = 512B row
  const int jc   = lane * 2;            // matvec: column pair per lane

  int* __restrict__ ctr = (int*)ws + WS_CTR;
  const float* __restrict__ Mg = ws + WS_M;
  const float2 c2 = *(const float2*)(ws + WS_C + jc);

  float* __restrict__ pw = &p_sh[wid][0][0];
  int*   __restrict__ ow = off_sh[wid];

  int id0 = -1, id1 = -1, id2 = -1, id3 = -1;  // wave-uniform bag ids per slot
  int s = 0;

  for (;;) {
    int b = 0;
    if (lane == 0) b = atomicAdd(ctr, 1);
    b = __shfl(b, 0, 64);
    if (b >= NBAGS) break;

    const int len = lengths[b];
    if (lane < L_) ow[lane] = indices[b * L_ + lane] << 9;  // row byte offsets
    asm volatile("s_waitcnt lgkmcnt(0)" ::: "memory");      // wave-local publish

    const int t = b >> 13;              // 8192 bags per table
    const char* __restrict__ tab =
        (const char*)(tables + (size_t)t * (VOCAB_ * D_) + d0);

    float ax = 0.f, ay = 0.f, az = 0.f, aw = 0.f;
    int l = 0;
    for (; l + 15 < len; l += 16) {     // 8 x 1KB loads in flight
      const int o0 = ow[l +  0 + half];
      const int o1 = ow[l +  2 + half];
      const int o2 = ow[l +  4 + half];
      const int o3 = ow[l +  6 + half];
      const int o4 = ow[l +  8 + half];
      const int o5 = ow[l + 10 + half];
      const int o6 = ow[l + 12 + half];
      const int o7 = ow[l + 14 + half];
      const float4 v0 = *(const float4*)(tab + o0);
      const float4 v1 = *(const float4*)(tab + o1);
      const float4 v2 = *(const float4*)(tab + o2);
      const float4 v3 = *(const float4*)(tab + o3);
      const float4 v4 = *(const float4*)(tab + o4);
      const float4 v5 = *(const float4*)(tab + o5);
      const float4 v6 = *(const float4*)(tab + o6);
      const float4 v7 = *(const float4*)(tab + o7);
      ax += v0.x; ay += v0.y; az += v0.z; aw += v0.w;
      ax += v1.x; ay += v1.y; az += v1.z; aw += v1.w;
      ax += v2.x; ay += v2.y; az += v2.z; aw += v2.w;
      ax += v3.x; ay += v3.y; az += v3.z; aw += v3.w;
      ax += v4.x; ay += v4.y; az += v4.z; aw += v4.w;
      ax += v5.x; ay += v5.y; az += v5.z; aw += v5.w;
      ax += v6.x; ay += v6.y; az += v6.z; aw += v6.w;
      ax += v7.x; ay += v7.y; az += v7.z; aw += v7.w;
    }
    if (l + 7 < len) {                  // 8 positions, 4 loads
      const int o0 = ow[l + 0 + half];
      const int o1 = ow[l + 2 + half];
      const int o2 = ow[l + 4 + half];
      const int o3 = ow[l + 6 + half];
      const float4 v0 = *(const float4*)(tab + o0);
      const float4 v1 = *(const float4*)(tab + o1);
      const float4 v2 = *(const float4*)(tab + o2);
      const float4 v3 = *(const float4*)(tab + o3);
      ax += v0.x; ay += v0.y; az += v0.z; aw += v0.w;
      ax += v1.x; ay += v1.y; az += v1.z; aw += v1.w;
      ax += v2.x; ay += v2.y; az += v2.z; aw += v2.w;
      ax += v3.x; ay += v3.y; az += v3.z; aw += v3.w;
      l += 8;
    }
    if (l + 3 < len) {                  // 4 positions, 2 loads
      const int o0 = ow[l + 0 + half];
      const int o1 = ow[l + 2 + half];
      const float4 v0 = *(const float4*)(tab + o0);
      const float4 v1 = *(const float4*)(tab + o1);
      ax += v0.x; ay += v0.y; az += v0.z; aw += v0.w;
      ax += v1.x; ay += v1.y; az += v1.z; aw += v1.w;
      l += 4;
    }
    if (l + 1 < len) {                  // 2 positions, 1 load
      const float4 v = *(const float4*)(tab + ow[l + half]);
      ax += v.x; ay += v.y; az += v.z; aw += v.w;
      l += 2;
    }
    if (l < len && half == 0) {         // odd tail: even half covers it alone
      const float4 v = *(const float4*)(tab + ow[l]);
      ax += v.x; ay += v.y; az += v.z; aw += v.w;
    }
    ax += __shfl_xor(ax, 32, 64);
    ay += __shfl_xor(ay, 32, 64);
    az += __shfl_xor(az, 32, 64);
    aw += __shfl_xor(aw, 32, 64);
    if (half == 0)
      *(float4*)(pw + s * D_ + d0) = make_float4(ax, ay, az, aw);

    if (s == 0) id0 = b; else if (s == 1) id1 = b;
    else if (s == 2) id2 = b; else id3 = b;
    ++s;

    if (s == 4) {                       // 4-row matvec: rows share M loads
      asm volatile("s_waitcnt lgkmcnt(0)" ::: "memory");
      float2 a0 = c2, a1 = c2, a2 = c2, a3 = c2;
#pragma unroll 4
      for (int i = 0; i < D_; ++i) {
        const float2 m = *(const float2*)(Mg + i * D_ + jc);
        const float q0 = pw[0 * D_ + i];
        const float q1 = pw[1 * D_ + i];
        const float q2 = pw[2 * D_ + i];
        const float q3 = pw[3 * D_ + i];
        a0.x += q0 * m.x; a0.y += q0 * m.y;
        a1.x += q1 * m.x; a1.y += q1 * m.y;
        a2.x += q2 * m.x; a2.y += q2 * m.y;
        a3.x += q3 * m.x; a3.y += q3 * m.y;
      }
      *(float2*)&out[(size_t)id0 * D_ + jc] = a0;
      *(float2*)&out[(size_t)id1 * D_ + jc] = a1;
      *(float2*)&out[(size_t)id2 * D_ + jc] = a2;
      *(float2*)&out[(size_t)id3 * D_ + jc] = a3;
      s = 0;
    }
  }

  // flush 0..3 leftover rows (wave-uniform guards)
  asm volatile("s_waitcnt lgkmcnt(0)" ::: "memory");
  if (s > 0) {
    float2 a0 = c2;
#pragma unroll 4
    for (int i = 0; i < D_; ++i) {
      const float2 m = *(const float2*)(Mg + i * D_ + jc);
      a0.x += pw[0 * D_ + i] * m.x; a0.y += pw[0 * D_ + i] * m.y;
    }
    *(float2*)&out[(size_t)id0 * D_ + jc] = a0;
  }
  if (s > 1) {
    float2 a0 = c2;
#pragma unroll 4
    for (int i = 0; i < D_; ++i) {
      const float2 m = *(const float2*)(Mg + i * D_ + jc);
      a0.x += pw[1 * D_ + i] * m.x; a0.y += pw[1 * D_ + i] * m.y;
    }
    *(float2*)&out[(size_t)id1 * D_ + jc] = a0;
  }
  if (s > 2) {
    float2 a0 = c2;
#pragma unroll 4
    for (int i = 0; i < D_; ++i) {
      const float2 m = *(const float2*)(Mg + i * D_ + jc);
      a0.x += pw[2 * D_ + i] * m.x; a0.y += pw[2 * D_ + i] * m.y;
    }
    *(float2*)&out[(size_t)id2 * D_ + jc] = a0;
  }
}

extern "C" void kernel_launch(void* const* d_in, const int* in_sizes, int n_in,
                              void* d_out, int out_size, void* d_ws, size_t ws_size,
                              hipStream_t stream) {
  const int*   indices = (const int*)d_in[0];
  const int*   lengths = (const int*)d_in[1];
  const float* tables  = (const float*)d_in[2];
  const float* W1      = (const float*)d_in[3];
  const float* b1      = (const float*)d_in[4];
  const float* W2      = (const float*)d_in[5];
  const float* b2      = (const float*)d_in[6];
  const float* W3      = (const float*)d_in[7];
  const float* b3      = (const float*)d_in[8];
  float*       out     = (float*)d_out;
  float*       ws      = (float*)d_ws;

  combine<<<D_ + 1, D_, 0, stream>>>(W1, W2, W3, b1, b2, b3, ws);
  // 1024 blocks = 4 blocks/CU guaranteed resident; work-stealing makes grid
  // size non-critical (waves loop until the global counter is exhausted).
  fused<<<1024, 256, 0, stream>>>(indices, lengths, tables, ws, out);
}

// Round 3
// 346.197 us; speedup vs baseline: 1.9694x; 1.9694x over previous
//
#include <hip/hip_runtime.h>

// TestEBCModel: jagged embedding gather + SUM pool (T=4,B=8192,L=50,VOCAB=100000,D=128)
// followed by 3 stacked Linear(D,D) with no activation.
// Affine fold: M = W1^T W2^T W3^T, c = (b1 W2^T + b2) W3^T + b3; fused kernel does
// pool + single matvec per row.
// R6: R4 shell (block-staged indices, LDS steal counter, ROWS=16, grid=2048 -> one
// residency round, phase-2 unchanged) + paired-bag gather: each wave steals TWO bags
// and interleaves their load streams (4x1KB in flight, two independent accumulator
// sets), amortizing the steal/reduce/write bubble over 2 bags and breaking the
// per-bag serial chain. R5 post-mortem: global-atomic stealing + per-bag index
// loads + grid=1024 destroyed concurrency (455us @ 44% occ); bytes unchanged.

#define T_ 4
#define B_ 8192
#define L_ 50
#define VOCAB_ 100000
#define D_ 128
#define ROWS 16        // bags per block in fused kernel (even: pair-steal safe)
#define NBAGS (T_ * B_)

// ws layout (floats): M[16384] | c[128]
#define WS_M  0
#define WS_C  16384

// ---- merged combine: M = (W1^T W2^T) W3^T ; c = ((b1 W2^T + b2)) W3^T + b3 ----
// blocks 0..127 compute M row i; block 128 computes c. Branch is block-uniform.
__global__ __launch_bounds__(128) void combine(const float* __restrict__ W1,
                                               const float* __restrict__ W2,
                                               const float* __restrict__ W3,
                                               const float* __restrict__ b1,
                                               const float* __restrict__ b2,
                                               const float* __restrict__ b3,
                                               float* __restrict__ ws) {
  __shared__ float a1[D_];
  const int j = threadIdx.x;
  const int i = blockIdx.x;
  if (i < D_) {
    float acc = 0.f;
    for (int k = 0; k < D_; ++k)
      acc += W1[k * D_ + i] * W2[j * D_ + k];
    a1[j] = acc;
    __syncthreads();
    float m = 0.f;
    for (int k = 0; k < D_; ++k)
      m += a1[k] * W3[j * D_ + k];
    ws[WS_M + i * D_ + j] = m;
  } else {
    float c1 = b2[j];
    for (int k = 0; k < D_; ++k)
      c1 += b1[k] * W2[j * D_ + k];
    a1[j] = c1;
    __syncthreads();
    float c = b3[j];
    for (int k = 0; k < D_; ++k)
      c += a1[k] * W3[j * D_ + k];
    ws[WS_C + j] = c;
  }
}

// ---- fused: paired-bag interleaved gather + block matvec ----
__global__ __launch_bounds__(256, 8) void fused(const int* __restrict__ indices,
                                                const int* __restrict__ lengths,
                                                const float* __restrict__ tables,
                                                const float* __restrict__ ws,
                                                float* __restrict__ out) {
  __shared__ __align__(16) float pooled_sh[ROWS][D_];
  __shared__ int off_sh[ROWS][L_];   // pre-shifted byte offsets (idx<<9)
  __shared__ int len_sh[ROWS];
  __shared__ int bag_ctr;

  const int tid = threadIdx.x;
  const int g0  = blockIdx.x * ROWS;

  if (tid == 0) bag_ctr = 0;
  for (int k = tid; k < ROWS * L_; k += 256)
    off_sh[k / L_][k % L_] = indices[g0 * L_ + k] << 9;
  if (tid < ROWS) len_sh[tid] = lengths[g0 + tid];
  __syncthreads();

  // phase 1: waves steal PAIRS of bags; interleave the two gather streams.
  {
    const int lane = tid & 63;
    const int half = lane >> 5;          // 0: even positions, 1: odd positions
    const int d0   = (lane & 31) * 4;    // 4 floats/lane, 32 lanes = 512B row
    const int t    = g0 >> 13;           // table id; block never spans tables
    const char* __restrict__ tab =
        (const char*)(tables + (size_t)t * (VOCAB_ * D_) + d0);

    for (;;) {
      int pr = 0;
      if (lane == 0) pr = atomicAdd(&bag_ctr, 2);
      pr = __shfl(pr, 0, 64);
      if (pr >= ROWS) break;           // ROWS even -> pr+1 always valid
      const int pA = pr, pB = pr + 1;
      const int lenA = len_sh[pA], lenB = len_sh[pB];
      const int* __restrict__ ilA = off_sh[pA];
      const int* __restrict__ ilB = off_sh[pB];

      float aAx = 0.f, aAy = 0.f, aAz = 0.f, aAw = 0.f;
      float aBx = 0.f, aBy = 0.f, aBz = 0.f, aBw = 0.f;
      int la = 0, lb = 0;

      // paired loop: 4 positions per bag per iter -> 4x1KB loads in flight,
      // two independent accumulation chains (no cross-bag dependency).
      while (la + 3 < lenA && lb + 3 < lenB) {
        const int oA0 = ilA[la + 0 + half];
        const int oA1 = ilA[la + 2 + half];
        const int oB0 = ilB[lb + 0 + half];
        const int oB1 = ilB[lb + 2 + half];
        const float4 vA0 = *(const float4*)(tab + oA0);
        const float4 vA1 = *(const float4*)(tab + oA1);
        const float4 vB0 = *(const float4*)(tab + oB0);
        const float4 vB1 = *(const float4*)(tab + oB1);
        aAx += vA0.x; aAy += vA0.y; aAz += vA0.z; aAw += vA0.w;
        aAx += vA1.x; aAy += vA1.y; aAz += vA1.z; aAw += vA1.w;
        aBx += vB0.x; aBy += vB0.y; aBz += vB0.z; aBw += vB0.w;
        aBx += vB1.x; aBy += vB1.y; aBz += vB1.z; aBw += vB1.w;
        la += 4; lb += 4;
      }

      // tails: R4 ladder (8/4/2/1 positions), one bag at a time.
      {
        const int* __restrict__ il = ilA;
        int l = la; const int len = lenA;
        for (; l + 7 < len; l += 8) {
          const int o0 = il[l + 0 + half];
          const int o1 = il[l + 2 + half];
          const int o2 = il[l + 4 + half];
          const int o3 = il[l + 6 + half];
          const float4 v0 = *(const float4*)(tab + o0);
          const float4 v1 = *(const float4*)(tab + o1);
          const float4 v2 = *(const float4*)(tab + o2);
          const float4 v3 = *(const float4*)(tab + o3);
          aAx += v0.x; aAy += v0.y; aAz += v0.z; aAw += v0.w;
          aAx += v1.x; aAy += v1.y; aAz += v1.z; aAw += v1.w;
          aAx += v2.x; aAy += v2.y; aAz += v2.z; aAw += v2.w;
          aAx += v3.x; aAy += v3.y; aAz += v3.z; aAw += v3.w;
        }
        if (l + 3 < len) {
          const int o0 = il[l + 0 + half];
          const int o1 = il[l + 2 + half];
          const float4 v0 = *(const float4*)(tab + o0);
          const float4 v1 = *(const float4*)(tab + o1);
          aAx += v0.x; aAy += v0.y; aAz += v0.z; aAw += v0.w;
          aAx += v1.x; aAy += v1.y; aAz += v1.z; aAw += v1.w;
          l += 4;
        }
        if (l + 1 < len) {
          const float4 v = *(const float4*)(tab + il[l + half]);
          aAx += v.x; aAy += v.y; aAz += v.z; aAw += v.w;
          l += 2;
        }
        if (l < len && half == 0) {
          const float4 v = *(const float4*)(tab + il[l]);
          aAx += v.x; aAy += v.y; aAz += v.z; aAw += v.w;
        }
      }
      {
        const int* __restrict__ il = ilB;
        int l = lb; const int len = lenB;
        for (; l + 7 < len; l += 8) {
          const int o0 = il[l + 0 + half];
          const int o1 = il[l + 2 + half];
          const int o2 = il[l + 4 + half];
          const int o3 = il[l + 6 + half];
          const float4 v0 = *(const float4*)(tab + o0);
          const float4 v1 = *(const float4*)(tab + o1);
          const float4 v2 = *(const float4*)(tab + o2);
          const float4 v3 = *(const float4*)(tab + o3);
          aBx += v0.x; aBy += v0.y; aBz += v0.z; aBw += v0.w;
          aBx += v1.x; aBy += v1.y; aBz += v1.z; aBw += v1.w;
          aBx += v2.x; aBy += v2.y; aBz += v2.z; aBw += v2.w;
          aBx += v3.x; aBy += v3.y; aBz += v3.z; aBw += v3.w;
        }
        if (l + 3 < len) {
          const int o0 = il[l + 0 + half];
          const int o1 = il[l + 2 + half];
          const float4 v0 = *(const float4*)(tab + o0);
          const float4 v1 = *(const float4*)(tab + o1);
          aBx += v0.x; aBy += v0.y; aBz += v0.z; aBw += v0.w;
          aBx += v1.x; aBy += v1.y; aBz += v1.z; aBw += v1.w;
          l += 4;
        }
        if (l + 1 < len) {
          const float4 v = *(const float4*)(tab + il[l + half]);
          aBx += v.x; aBy += v.y; aBz += v.z; aBw += v.w;
          l += 2;
        }
        if (l < len && half == 0) {
          const float4 v = *(const float4*)(tab + il[l]);
          aBx += v.x; aBy += v.y; aBz += v.z; aBw += v.w;
        }
      }

      // fold halves; lanes 0-31 own full row sums; contiguous b128 writes.
      aAx += __shfl_xor(aAx, 32, 64);
      aAy += __shfl_xor(aAy, 32, 64);
      aAz += __shfl_xor(aAz, 32, 64);
      aAw += __shfl_xor(aAw, 32, 64);
      aBx += __shfl_xor(aBx, 32, 64);
      aBy += __shfl_xor(aBy, 32, 64);
      aBz += __shfl_xor(aBz, 32, 64);
      aBw += __shfl_xor(aBw, 32, 64);
      if (half == 0) {
        *(float4*)&pooled_sh[pA][d0] = make_float4(aAx, aAy, aAz, aAw);
        *(float4*)&pooled_sh[pB][d0] = make_float4(aBx, aBy, aBz, aBw);
      }
    }
  }
  __syncthreads();

  // phase 2: out[g0+r][j] = c[j] + sum_i pooled[r][i] * M[i][j]
  // 2 cols x 4 rows per thread: per i, 1 float2 M load (wave = 512B coalesced,
  // L1/L2-hot), 4 broadcast LDS reads, 8 FMAs.
  const int jc = (tid & 63) * 2;           // column pair
  const int rh = (tid >> 6) * 4;           // rows rh..rh+3 (wave-uniform)
  const float* __restrict__ Mg = ws + WS_M;
  const float2 c2 = *(const float2*)(ws + WS_C + jc);
  float2 a0 = c2, a1 = c2, a2 = c2, a3 = c2;
#pragma unroll 4
  for (int i = 0; i < D_; ++i) {
    const float2 m = *(const float2*)(Mg + i * D_ + jc);
    const float p0 = pooled_sh[rh + 0][i];
    const float p1 = pooled_sh[rh + 1][i];
    const float p2 = pooled_sh[rh + 2][i];
    const float p3 = pooled_sh[rh + 3][i];
    a0.x += p0 * m.x; a0.y += p0 * m.y;
    a1.x += p1 * m.x; a1.y += p1 * m.y;
    a2.x += p2 * m.x; a2.y += p2 * m.y;
    a3.x += p3 * m.x; a3.y += p3 * m.y;
  }
  *(float2*)&out[(size_t)(g0 + rh + 0) * D_ + jc] = a0;
  *(float2*)&out[(size_t)(g0 + rh + 1) * D_ + jc] = a1;
  *(float2*)&out[(size_t)(g0 + rh + 2) * D_ + jc] = a2;
  *(float2*)&out[(size_t)(g0 + rh + 3) * D_ + jc] = a3;
}

extern "C" void kernel_launch(void* const* d_in, const int* in_sizes, int n_in,
                              void* d_out, int out_size, void* d_ws, size_t ws_size,
                              hipStream_t stream) {
  const int*   indices = (const int*)d_in[0];
  const int*   lengths = (const int*)d_in[1];
  const float* tables  = (const float*)d_in[2];
  const float* W1      = (const float*)d_in[3];
  const float* b1      = (const float*)d_in[4];
  const float* W2      = (const float*)d_in[5];
  const float* b2      = (const float*)d_in[6];
  const float* W3      = (const float*)d_in[7];
  const float* b3      = (const float*)d_in[8];
  float*       out     = (float*)d_out;
  float*       ws      = (float*)d_ws;

  combine<<<D_ + 1, D_, 0, stream>>>(W1, W2, W3, b1, b2, b3, ws);
  fused<<<NBAGS / ROWS, 256, 0, stream>>>(indices, lengths, tables, ws, out);
}